// Round 4
// baseline (10952.822 us; speedup 1.0000x reference)
//
#include <hip/hip_runtime.h>
#include <cstdint>

#define N_PTS 8192
#define M_PTS 4096
#define BS 4
#define CH 64
#define KNN 32
// radius*radius evaluated in Python float (f64): 0.2*0.2
#define R2D (0.2 * 0.2)

#define FPS_T 512          // threads in fps block
#define PPT (N_PTS / FPS_T) // 16 points per thread
#define NW (FPS_T / 64)    // 8 waves

struct __align__(16) Cand { double v; int idx; int pad; };

// ---------------- FPS: one block per batch ----------------
// Exact-f64 decision chain with f32 prefilter; single barrier per iteration.
__global__ __launch_bounds__(FPS_T, 2) void fps_kernel(const float* __restrict__ xyz,
                                                       float* __restrict__ child_xyz) {
  __shared__ float sx[N_PTS], sy[N_PTS], sz[N_PTS];
  __shared__ Cand scand[2][NW];

  const int b = blockIdx.x;
  const int t = threadIdx.x;
  const int lane = t & 63;
  const int wid  = t >> 6;
  const float* p = xyz + (size_t)b * N_PTS * 3;

  for (int e = t; e < N_PTS * 3; e += FPS_T) {
    float v = p[e];
    int i = e / 3, k = e - i * 3;
    if (k == 0) sx[i] = v; else if (k == 1) sy[i] = v; else sz[i] = v;
  }
  __syncthreads();

  // own 16 points: f32 coords, exact f64 min-dist + f32 mirror
  float pxf[PPT], pyf[PPT], pzf[PPT], md32[PPT];
  double md64[PPT];
#pragma unroll
  for (int q = 0; q < PPT; ++q) {
    int i = t + q * FPS_T;
    pxf[q] = sx[i]; pyf[q] = sy[i]; pzf[q] = sz[i];
    md64[q] = 1e10; md32[q] = (float)1e10;
  }

  int cur = 0;
  for (int it = 0; it < M_PTS; ++it) {
    const float lxf = sx[cur], lyf = sy[cur], lzf = sz[cur];
    if (t == 0) {
      float* o = child_xyz + ((size_t)b * M_PTS + it) * 3;
      o[0] = lxf; o[1] = lyf; o[2] = lzf;
    }
    const double lxd = (double)lxf, lyd = (double)lyf, lzd = (double)lzf;

    // f32 prefilter (contraction fine; margin covers ~2^-21 rel error),
    // exact f64 update only for flagged q-slices
#pragma unroll
    for (int q = 0; q < PPT; ++q) {
      float dxf = pxf[q] - lxf, dyf = pyf[q] - lyf, dzf = pzf[q] - lzf;
      float d2f = dxf * dxf + dyf * dyf + dzf * dzf;
      bool c = d2f <= md32[q] * 1.00001f + 1e-30f;
      if (__any(c)) {
        if (c) {
          double dx = (double)pxf[q] - lxd;
          double dy = (double)pyf[q] - lyd;
          double dz = (double)pzf[q] - lzd;
          double d2d = dx * dx + dy * dy + dz * dz;
          if (d2d < md64[q]) { md64[q] = d2d; md32[q] = (float)d2d; }
        }
      }
    }

    // local argmax: f32 max, then f64-lex select among f32 ties.
    // (f64->f32 rounding is monotone: unique f32 max => that q also has the
    //  strictly largest f64; ties resolved exactly in f64, earliest q wins.)
    float bv32 = md32[0];
#pragma unroll
    for (int q = 1; q < PPT; ++q) bv32 = fmaxf(bv32, md32[q]);
    double bv64 = -1.0; int bi = 0x7fffffff;
#pragma unroll
    for (int q = 0; q < PPT; ++q) {
      bool m = (md32[q] == bv32) && (md64[q] > bv64);
      if (m) { bv64 = md64[q]; bi = t + q * FPS_T; }
    }

    // wave argmax butterfly, exact f64 lex (tie -> smaller index)
#pragma unroll
    for (int off = 32; off; off >>= 1) {
      double ov = __shfl_xor(bv64, off);
      int    oi = __shfl_xor(bi, off);
      if (ov > bv64 || (ov == bv64 && oi < bi)) { bv64 = ov; bi = oi; }
    }

    const int pb = it & 1;  // parity double-buffer -> one barrier per iter
    if (lane == 0) { scand[pb][wid].v = bv64; scand[pb][wid].idx = bi; }
    __syncthreads();

    // all threads redundantly scan the 8 wave candidates (uniform broadcast reads)
    double best = scand[pb][0].v; int bidx = scand[pb][0].idx;
#pragma unroll
    for (int w = 1; w < NW; ++w) {
      double v = scand[pb][w].v; int i2 = scand[pb][w].idx;
      if (v > best || (v == best && i2 < bidx)) { best = v; bidx = i2; }
    }
    cur = bidx;
  }
}

// ---------------- feats (b,c,n) -> featsT (b,n,c) ----------------
__global__ __launch_bounds__(256) void transpose_kernel(const float* __restrict__ feats,
                                                        float* __restrict__ featsT) {
  __shared__ float tile[CH][65];
  const int b = blockIdx.y;
  const int i0 = blockIdx.x * 64;
  const int t = threadIdx.x;
  const float* src = feats + (size_t)b * CH * N_PTS;
#pragma unroll
  for (int r = 0; r < 16; ++r) {
    int e = t + r * 256;
    int c = e >> 6, ii = e & 63;
    tile[c][ii] = src[(size_t)c * N_PTS + i0 + ii];
  }
  __syncthreads();
  float* dst = featsT + ((size_t)b * N_PTS + i0) * CH;
#pragma unroll
  for (int r = 0; r < 16; ++r) {
    int e = t + r * 256;
    int ii = e >> 6, c = e & 63;
    dst[(size_t)ii * CH + c] = tile[c][ii];
  }
}

// ---------------- ball query (first-K ascending index) + feature max, fused ----------------
__global__ __launch_bounds__(1024) void ballgroup_kernel(const float* __restrict__ xyz,
                                                         const float* __restrict__ child_xyz,
                                                         const float* __restrict__ featsrc,
                                                         float* __restrict__ child_feats,
                                                         int useT) {
  __shared__ float sx[N_PTS], sy[N_PTS], sz[N_PTS];
  __shared__ int slist[16][KNN];
  const int b = blockIdx.y;
  const int t = threadIdx.x;
  const int lane = t & 63, wid = t >> 6;
  const float* p = xyz + (size_t)b * N_PTS * 3;
  for (int e = t; e < N_PTS * 3; e += 1024) {
    float v = p[e];
    int i = e / 3, k = e - i * 3;
    if (k == 0) sx[i] = v; else if (k == 1) sy[i] = v; else sz[i] = v;
  }
  __syncthreads();

  const int j = blockIdx.x * 16 + wid;           // one wave per ball
  const float* cc = child_xyz + ((size_t)b * M_PTS + j) * 3;
  const double cx = (double)cc[0], cy = (double)cc[1], cz = (double)cc[2];

  int taken = 0;
  for (int i0 = 0; i0 < N_PTS && taken < KNN; i0 += 64) {
    const int i = i0 + lane;
    double dx = cx - (double)sx[i], dy = cy - (double)sy[i], dz = cz - (double)sz[i];
    double d2 = dx * dx + dy * dy + dz * dz;
    const bool hit = d2 <= R2D;
    const unsigned long long msk = __ballot(hit);
    if (msk) {
      int slot = taken + __popcll(msk & ((1ull << lane) - 1ull));
      if (hit && slot < KNN) slist[wid][slot] = i;
      taken += (int)__popcll(msk);
    }
  }
  int cnt = taken < KNN ? taken : KNN;
  if (cnt == 0) { if (lane == 0) slist[wid][0] = 0; cnt = 1; }  // safety (self-hit guarantees >=1)

  float acc = -INFINITY;
  for (int q = 0; q < cnt; ++q) {
    const int idx = slist[wid][q];
    float v = useT ? featsrc[((size_t)b * N_PTS + idx) * CH + lane]
                   : featsrc[((size_t)b * CH + lane) * N_PTS + idx];
    acc = fmaxf(acc, v);
  }
  child_feats[((size_t)b * CH + lane) * M_PTS + j] = acc;
}

extern "C" void kernel_launch(void* const* d_in, const int* in_sizes, int n_in,
                              void* d_out, int out_size, void* d_ws, size_t ws_size,
                              hipStream_t stream) {
  const float* xyz   = (const float*)d_in[0];
  const float* feats = (const float*)d_in[1];
  float* out = (float*)d_out;
  float* child_xyz   = out;
  float* child_feats = out + (size_t)BS * M_PTS * 3;
  float* featsT = (float*)d_ws;
  const int useT = ws_size >= (size_t)BS * N_PTS * CH * sizeof(float);

  fps_kernel<<<BS, FPS_T, 0, stream>>>(xyz, child_xyz);
  if (useT) transpose_kernel<<<dim3(N_PTS / 64, BS), 256, 0, stream>>>(feats, featsT);
  ballgroup_kernel<<<dim3(M_PTS / 16, BS), 1024, 0, stream>>>(
      xyz, child_xyz, useT ? featsT : feats, child_feats, useT);
}

// Round 5
// 5496.217 us; speedup vs baseline: 1.9928x; 1.9928x over previous
//
#include <hip/hip_runtime.h>
#include <cstdint>

#define N_PTS 8192
#define M_PTS 4096
#define BS 4
#define CH 64
#define KNN 32
// radius*radius evaluated in Python float (f64): 0.2*0.2
#define R2D (0.2 * 0.2)

// ---------------- FPS: one block per batch, f64-exact decisions ----------------
// R3 update (bit-matching np f64 chain) + cheap reduction:
//   f32-proxy butterflies with exact-f64 fallback on proxy ties, 1 barrier/iter.
__global__ __launch_bounds__(1024) void fps_kernel(const float* __restrict__ xyz,
                                                   float* __restrict__ child_xyz) {
  __shared__ float  sx[N_PTS], sy[N_PTS], sz[N_PTS];
  __shared__ float  sproxy[2][16];
  __shared__ double sval[2][16];
  __shared__ int    sidx[2][16];

  const int b = blockIdx.x;
  const int t = threadIdx.x;
  const int lane = t & 63;
  const int wid  = t >> 6;
  const float* p = xyz + (size_t)b * N_PTS * 3;

  for (int e = t; e < N_PTS * 3; e += 1024) {
    float v = p[e];
    int i = e / 3, k = e - i * 3;
    if (k == 0) sx[i] = v; else if (k == 1) sy[i] = v; else sz[i] = v;
  }
  __syncthreads();

  // each thread owns 8 points; coords & running min_d2 in f64 (exactly as R3)
  double px[8], py[8], pz[8], md[8];
#pragma unroll
  for (int q = 0; q < 8; ++q) {
    int i = t + (q << 10);
    px[q] = (double)sx[i]; py[q] = (double)sy[i]; pz[q] = (double)sz[i];
    md[q] = 1e10;
  }

  int cur = 0;
  for (int it = 0; it < M_PTS; ++it) {
    const float lxf = sx[cur], lyf = sy[cur], lzf = sz[cur];
    if (t == 0) {
      float* o = child_xyz + ((size_t)b * M_PTS + it) * 3;
      o[0] = lxf; o[1] = lyf; o[2] = lzf;
    }
    const double lx = (double)lxf, ly = (double)lyf, lz = (double)lzf;
#pragma unroll
    for (int q = 0; q < 8; ++q) {
      double dx = px[q] - lx, dy = py[q] - ly, dz = pz[q] - lz;
      double d2 = dx * dx + dy * dy + dz * dz;  // products exact in f64
      md[q] = fmin(md[q], d2);
    }
    // local argmax, exact f64, earliest owned index on ties
    double bv = md[0];
#pragma unroll
    for (int q = 1; q < 8; ++q) bv = fmax(bv, md[q]);
    int bi = t;
#pragma unroll
    for (int q = 7; q >= 0; --q) if (md[q] == bv) bi = t + (q << 10);

    // ---- wave reduce: f32 value-only butterfly + exact fallback ----
    // monotone f64->f32: the f64 winner always has proxy==wmax; equal f64s
    // share a proxy, so any ambiguity forces popcount>1 -> exact path.
    float proxy = (float)bv;
    float wmax = proxy;
#pragma unroll
    for (int off = 32; off; off >>= 1) wmax = fmaxf(wmax, __shfl_xor(wmax, off));
    const unsigned long long m = __ballot(proxy == wmax);
    const int pb = it & 1;
    if (__popcll(m) == 1) {                    // wave-uniform branch
      if (proxy == wmax) { sproxy[pb][wid] = proxy; sval[pb][wid] = bv; sidx[pb][wid] = bi; }
    } else {                                   // rare: exact f64-lex butterfly
#pragma unroll
      for (int off = 32; off; off >>= 1) {
        double ov = __shfl_xor(bv, off);
        int    oi = __shfl_xor(bi, off);
        if (ov > bv || (ov == bv && oi < bi)) { bv = ov; bi = oi; }
      }
      if (lane == 0) { sproxy[pb][wid] = (float)bv; sval[pb][wid] = bv; sidx[pb][wid] = bi; }
    }
    __syncthreads();   // single barrier per iteration (parity double-buffer)

    // ---- cross-wave: spread 16 wave-bests over lanes, f32 butterfly ----
    float pm = sproxy[pb][lane & 15];
    int   pi = sidx[pb][lane & 15];
    float gmax = pm;
#pragma unroll
    for (int off = 8; off; off >>= 1) gmax = fmaxf(gmax, __shfl_xor(gmax, off));
    const unsigned long long gm = __ballot((lane < 16) && (pm == gmax));
    if (__popcll(gm) == 1) {                   // block-uniform branch
      int w = __ffsll(gm) - 1;
      cur = __shfl(pi, w);
    } else {                                   // rare: exact f64 lex over tied waves
      double bestv = -1.0; int besti = 0x7fffffff;
      for (int w = 0; w < 16; ++w) if ((gm >> w) & 1) {
        double v = sval[pb][w]; int ii = sidx[pb][w];
        if (v > bestv || (v == bestv && ii < besti)) { bestv = v; besti = ii; }
      }
      cur = besti;
    }
  }
}

// ---------------- feats (b,c,n) -> featsT (b,n,c) ----------------
__global__ __launch_bounds__(256) void transpose_kernel(const float* __restrict__ feats,
                                                        float* __restrict__ featsT) {
  __shared__ float tile[CH][65];
  const int b = blockIdx.y;
  const int i0 = blockIdx.x * 64;
  const int t = threadIdx.x;
  const float* src = feats + (size_t)b * CH * N_PTS;
#pragma unroll
  for (int r = 0; r < 16; ++r) {
    int e = t + r * 256;
    int c = e >> 6, ii = e & 63;
    tile[c][ii] = src[(size_t)c * N_PTS + i0 + ii];
  }
  __syncthreads();
  float* dst = featsT + ((size_t)b * N_PTS + i0) * CH;
#pragma unroll
  for (int r = 0; r < 16; ++r) {
    int e = t + r * 256;
    int ii = e >> 6, c = e & 63;
    dst[(size_t)ii * CH + c] = tile[c][ii];
  }
}

// ---------------- ball query (first-K ascending index) + feature max, fused ----------------
__global__ __launch_bounds__(1024) void ballgroup_kernel(const float* __restrict__ xyz,
                                                         const float* __restrict__ child_xyz,
                                                         const float* __restrict__ featsrc,
                                                         float* __restrict__ child_feats,
                                                         int useT) {
  __shared__ float sx[N_PTS], sy[N_PTS], sz[N_PTS];
  __shared__ int slist[16][KNN];
  const int b = blockIdx.y;
  const int t = threadIdx.x;
  const int lane = t & 63, wid = t >> 6;
  const float* p = xyz + (size_t)b * N_PTS * 3;
  for (int e = t; e < N_PTS * 3; e += 1024) {
    float v = p[e];
    int i = e / 3, k = e - i * 3;
    if (k == 0) sx[i] = v; else if (k == 1) sy[i] = v; else sz[i] = v;
  }
  __syncthreads();

  const int j = blockIdx.x * 16 + wid;           // one wave per ball
  const float* cc = child_xyz + ((size_t)b * M_PTS + j) * 3;
  const double cx = (double)cc[0], cy = (double)cc[1], cz = (double)cc[2];

  int taken = 0;
  for (int i0 = 0; i0 < N_PTS && taken < KNN; i0 += 64) {
    const int i = i0 + lane;
    double dx = cx - (double)sx[i], dy = cy - (double)sy[i], dz = cz - (double)sz[i];
    double d2 = dx * dx + dy * dy + dz * dz;
    const bool hit = d2 <= R2D;
    const unsigned long long msk = __ballot(hit);
    if (msk) {
      int slot = taken + __popcll(msk & ((1ull << lane) - 1ull));
      if (hit && slot < KNN) slist[wid][slot] = i;
      taken += (int)__popcll(msk);
    }
  }
  int cnt = taken < KNN ? taken : KNN;
  if (cnt == 0) { if (lane == 0) slist[wid][0] = 0; cnt = 1; }  // safety (self-hit guarantees >=1)

  float acc = -INFINITY;
  for (int q = 0; q < cnt; ++q) {
    const int idx = slist[wid][q];
    float v = useT ? featsrc[((size_t)b * N_PTS + idx) * CH + lane]
                   : featsrc[((size_t)b * CH + lane) * N_PTS + idx];
    acc = fmaxf(acc, v);
  }
  child_feats[((size_t)b * CH + lane) * M_PTS + j] = acc;
}

extern "C" void kernel_launch(void* const* d_in, const int* in_sizes, int n_in,
                              void* d_out, int out_size, void* d_ws, size_t ws_size,
                              hipStream_t stream) {
  const float* xyz   = (const float*)d_in[0];
  const float* feats = (const float*)d_in[1];
  float* out = (float*)d_out;
  float* child_xyz   = out;
  float* child_feats = out + (size_t)BS * M_PTS * 3;
  float* featsT = (float*)d_ws;
  const int useT = ws_size >= (size_t)BS * N_PTS * CH * sizeof(float);

  fps_kernel<<<BS, 1024, 0, stream>>>(xyz, child_xyz);
  if (useT) transpose_kernel<<<dim3(N_PTS / 64, BS), 256, 0, stream>>>(feats, featsT);
  ballgroup_kernel<<<dim3(M_PTS / 16, BS), 1024, 0, stream>>>(
      xyz, child_xyz, useT ? featsT : feats, child_feats, useT);
}